// Round 26
// baseline (153.812 us; speedup 1.0000x reference)
//
#include <hip/hip_runtime.h>

#define BS_   4
#define SEQ_  4096
#define DIM_  768
#define NH_   12
#define HD_   64
#define LK_   256

typedef __attribute__((ext_vector_type(8))) short          bf8;
typedef __attribute__((ext_vector_type(8))) unsigned short us8;
typedef __attribute__((ext_vector_type(4))) unsigned short us4;
typedef __attribute__((ext_vector_type(4))) float          f32x4;
typedef __attribute__((ext_vector_type(4))) unsigned int   u32x4;

typedef unsigned int u32g __attribute__((address_space(1)));
typedef unsigned int u32l __attribute__((address_space(3)));

#define LOG2E 1.44269504088896340736f

__device__ __forceinline__ unsigned short f2bf(float f) {
  unsigned u = __builtin_bit_cast(unsigned, f);
  u += 0x7fffu + ((u >> 16) & 1u);   // round-to-nearest-even
  return (unsigned short)(u >> 16);
}

__device__ __forceinline__ us8 cvt8(const float* __restrict__ p) {
  const float4 a = *(const float4*)p;
  const float4 b = *(const float4*)(p + 4);
  us8 r;
  r[0] = f2bf(a.x); r[1] = f2bf(a.y); r[2] = f2bf(a.z); r[3] = f2bf(a.w);
  r[4] = f2bf(b.x); r[5] = f2bf(b.y); r[6] = f2bf(b.z); r[7] = f2bf(b.w);
  return r;
}

__device__ __forceinline__ f32x4 max4(f32x4 a, f32x4 b) {
  f32x4 r;
  r[0] = fmaxf(a[0], b[0]); r[1] = fmaxf(a[1], b[1]);
  r[2] = fmaxf(a[2], b[2]); r[3] = fmaxf(a[3], b[3]);
  return r;
}

// raw transcendental (r6/r21-verified): input <= 0 after max-subtract, safe
__device__ __forceinline__ float fexp2(float x) {
  float r; asm("v_exp_f32 %0, %1" : "=v"(r) : "v"(x)); return r;
}
// packed f32x2 -> bf16x2, RNE (r21-verified at the accuracy floor)
__device__ __forceinline__ unsigned cvtpk(float lo, float hi) {
  unsigned r; asm("v_cvt_pk_bf16_f32 %0, %1, %2" : "=v"(r) : "v"(lo), "v"(hi));
  return r;
}

// ---------------------------------------------------------------------------
// Merged prep dispatch (384 threads) — r22 variant (best steady 45.96 us;
// 4 structural variants all land 46-50, prep is L3-latency-bound: frozen):
//  blocks 0..1023   : masked 16-window pool -> pK/pV + frac (compacted
//                     window list, 8 loads in flight).
//  blocks 1024..3455: bf16 conversion of query (-> Qbf) + weights (-> Wbf),
//                     two independent 32B chunks per thread.
// ---------------------------------------------------------------------------
__global__ __launch_bounds__(384) void prep_kernel(
    const float* __restrict__ key, const float* __restrict__ value,
    const float* __restrict__ mask, const float* __restrict__ query,
    const float* __restrict__ Wq, const float* __restrict__ Wk,
    const float* __restrict__ Wv, const float* __restrict__ Wo,
    unsigned short* __restrict__ pk, unsigned short* __restrict__ pv,
    float* __restrict__ frac,
    unsigned short* __restrict__ Qbf, unsigned short* __restrict__ Wbf)
{
  const int bid = blockIdx.x;
  const int tid = threadIdx.x;
  if (bid < 1024) {                    // ---- pool path
    const int b = bid >> 8;
    const int l = bid & 255;
    __shared__ float keep[16];
    __shared__ int   wlist[16];
    __shared__ float wwt[16];
    __shared__ int   nk4s;
    if (tid < 16) keep[tid] = (mask[b * SEQ_ + l * 16 + tid] >= 0.f) ? 1.f : 0.f;
    __syncthreads();
    if (tid == 0) {
      int n = 0; float cnt = 0.f;
      for (int w = 0; w < 16; ++w)
        if (keep[w] != 0.f) { wlist[n] = w; wwt[n] = 1.f; ++n; cnt += 1.f; }
      frac[b * LK_ + l] = cnt * (1.f / 16.f);
      const int n8 = (n + 7) & ~7;
      for (int i = n; i < n8; ++i) { wlist[i] = wlist[0]; wwt[i] = 0.f; }
      if (n == 0) for (int i = 0; i < 8; ++i) { wlist[i] = 0; wwt[i] = 0.f; }
      nk4s = (n == 0) ? 0 : n8;
    }
    __syncthreads();
    const int nk8 = nk4s;
    const int isV = tid >= 192;
    const int c = isV ? tid - 192 : tid;          // float4 chunk 0..191
    const float* src = isV ? value : key;
    const float* base = src + (size_t)(b * SEQ_ + l * 16) * DIM_ + c * 4;
    float4 acc = make_float4(0.f, 0.f, 0.f, 0.f);
    for (int i = 0; i < nk8; i += 8) {
      #pragma unroll
      for (int u = 0; u < 8; ++u) {
        const float4 v = *(const float4*)(base + (size_t)wlist[i + u] * DIM_);
        const float w = wwt[i + u];
        acc.x = fmaf(w, v.x, acc.x); acc.y = fmaf(w, v.y, acc.y);
        acc.z = fmaf(w, v.z, acc.z); acc.w = fmaf(w, v.w, acc.w);
      }
    }
    const float s = 1.f / 16.f;
    unsigned short* dst = isV ? pv : pk;
    us4 o4;
    o4[0] = f2bf(acc.x * s); o4[1] = f2bf(acc.y * s);
    o4[2] = f2bf(acc.z * s); o4[3] = f2bf(acc.w * s);
    *(us4*)(dst + (size_t)(b * LK_ + l) * DIM_ + c * 4) = o4;
    return;
  }
  // ---- conversion path: two chunks per thread, loads independent
  const int QN8 = (BS_ * SEQ_ * DIM_) / 8;        // 1572864
  const int WN8 = (DIM_ * DIM_) / 8;              // 73728
  const int i0 = (bid - 1024) * 768 + tid;
  #pragma unroll
  for (int u = 0; u < 2; ++u) {
    const int i = i0 + u * 384;
    if (i < QN8) { *(us8*)(Qbf + (size_t)i * 8) = cvt8(query + (size_t)i * 8); continue; }
    int j = i - QN8;
    const float* src; unsigned short* dst;
    if      (j <     WN8) { src = Wq; dst = Wbf;                   }
    else if (j < 2 * WN8) { src = Wk; dst = Wbf + DIM_*DIM_;     j -=     WN8; }
    else if (j < 3 * WN8) { src = Wv; dst = Wbf + 2*DIM_*DIM_;   j -= 2 * WN8; }
    else if (j < 4 * WN8) { src = Wo; dst = Wbf + 3*DIM_*DIM_;   j -= 3 * WN8; }
    else continue;
    *(us8*)(dst + (size_t)j * 8) = cvt8(src + (size_t)j * 8);
  }
}

// ---------------------------------------------------------------------------
// C = A @ B^T (+ epilogue).  128x128 tile, BK=32 (NT=24), 4 waves, 16x16x32
// bf16 MFMA, double-buffered LDS with COUNTED vmcnt (T3+T4 skeleton,
// r20-verified).  OCCUPANCY play: BK 64->32 halves LDS to 32 KB total ->
// 5 blocks/CU = 20 waves/CU (was 2 blocks/8 waves); in the counted-vmcnt
// regime drains are cheap waits, so TLP (inter-block phase overlap, m114)
// dominates the extra barrier count.
// PACKED-ROW swizzle (BK=32 rows are 64 B -> naive = 4-way conflict): two
// logical rows share a 128-B physical row; prow=row>>1, cp=(row&1)*4+chunk,
// phys pp = cp ^ (prow&7).  Source address applies the same permutation
// (dest stays linear tid*8 — the legal global_load_lds pattern); read side
// applies it identically (involution, both-sides rule).  Per bank-quad:
// exactly 8 lanes of the wave64 = the ds_read_b128 floor -> conflict-free.
// MODE 0: out_bf16 = (acc + bias[c]) * scale               (Q projection)
// MODE 2: out_f32  = acc + bias[c]                         (output projection)
// MODE 34: fused K/V projection pair, blockIdx.z selects Kf/Vf layouts.
// ---------------------------------------------------------------------------
template<int MODE, int SWZ>
__global__ __launch_bounds__(256) void gemm_bt(
    const void* __restrict__ Aptr_, const void* __restrict__ Bptr_,
    const float* __restrict__ bias, const float* __restrict__ bias2,
    const float* __restrict__ frac,
    void* __restrict__ Cout, float scale)
{
  constexpr int K  = DIM_;
  constexpr int BK = 32;
  constexpr int NT = K / BK;           // 24
  // 64 physical rows x 64 bf16 (two logical rows packed) = 8 KB per buffer
  __shared__ __align__(16) unsigned short lA[2][64 * 64];
  __shared__ __align__(16) unsigned short lB[2][64 * 64];
  const int tid  = threadIdx.x;
  const int lane = tid & 63;
  const int wave = tid >> 6;

  int bx, by;
  if (SWZ) {
    const int r = (blockIdx.x & 7) * 96 + (blockIdx.x >> 3);
    bx = r / 6; by = r % 6;
  } else {
    bx = blockIdx.x; by = blockIdx.y;
  }
  const int brow = bx * 128;
  const int bcol = by * 128;

  const unsigned short* A  = (const unsigned short*)Aptr_;
  const unsigned short* Bw = (const unsigned short*)Bptr_;
  const float* bb = bias;
  int isV = 0;
  if (MODE == 34) {
    isV = blockIdx.z;
    A  += (size_t)isV * (BS_ * LK_ * DIM_);    // pV follows pK
    Bw += (size_t)isV * (DIM_ * DIM_);         // Wv follows Wk
    if (isV) bb = bias2;
  }

  const int wr = (wave >> 1) * 64;
  const int wc = (wave & 1) * 64;
  const int fr = lane & 15;
  const int hi = lane >> 4;            // k-chunk 0..3 (8 bf16 each)

  f32x4 acc[4][4];
  #pragma unroll
  for (int i = 0; i < 4; ++i)
    #pragma unroll
    for (int j = 0; j < 4; ++j) acc[i][j] = (f32x4){0.f, 0.f, 0.f, 0.f};

  // staging geometry: slot -> (physical row prg, physical piece pp);
  // logical cp = pp ^ (prg&7); row = 2*prg + (cp>>2); k-chunk = cp&3.
  const int prg_lo = tid >> 3;         // 0..31 (shot-local physical row)
  const int pp_s   = tid & 7;

  auto STAGE = [&](int t, int b) {     // 4 VMEM instructions per thread
    const int k0 = t * BK;
    #pragma unroll
    for (int s = 0; s < 2; ++s) {
      const int prg = s * 32 + prg_lo;           // 0..63
      const int cp  = pp_s ^ (prg & 7);
      const int row = prg * 2 + (cp >> 2);       // logical row 0..127
      const int chk = (cp & 3) * 8;              // bf16 k-offset
      __builtin_amdgcn_global_load_lds(
          (const u32g*)(A + (size_t)(brow + row) * K + k0 + chk),
          (u32l*)&lA[b][s * 2048 + tid * 8], 16, 0, 0);
      __builtin_amdgcn_global_load_lds(
          (const u32g*)(Bw + (size_t)(bcol + row) * K + k0 + chk),
          (u32l*)&lB[b][s * 2048 + tid * 8], 16, 0, 0);
    }
  };

  auto COMPUTE = [&](int b) {
    bf8 af[4], bfv[4];
    #pragma unroll
    for (int mi = 0; mi < 4; ++mi) {
      const int r  = wr + mi * 16 + fr;
      const int pp = (hi + (r & 1) * 4) ^ ((r >> 1) & 7);
      af[mi] = *(const bf8*)&lA[b][(r >> 1) * 64 + pp * 8];
    }
    #pragma unroll
    for (int ni = 0; ni < 4; ++ni) {
      const int r  = wc + ni * 16 + fr;
      const int pp = (hi + (r & 1) * 4) ^ ((r >> 1) & 7);
      bfv[ni] = *(const bf8*)&lB[b][(r >> 1) * 64 + pp * 8];
    }
    #pragma unroll
    for (int mi = 0; mi < 4; ++mi)
      #pragma unroll
      for (int ni = 0; ni < 4; ++ni)
        acc[mi][ni] = __builtin_amdgcn_mfma_f32_16x16x32_bf16(af[mi], bfv[ni], acc[mi][ni], 0, 0, 0);
  };

  // ---- prologue: two tiles in flight, wait only for the first
  STAGE(0, 0);
  STAGE(1, 1);
  asm volatile("s_waitcnt vmcnt(4)" ::: "memory");
  __builtin_amdgcn_s_barrier();

  #pragma unroll 2
  for (int t = 0; t < NT; ++t) {
    COMPUTE(t & 1);
    if (t + 1 < NT) {
      __builtin_amdgcn_s_barrier();              // all waves done reading buf
      if (t + 2 < NT) {
        STAGE(t + 2, t & 1);                     // refill freed buffer
        asm volatile("s_waitcnt vmcnt(4)" ::: "memory");  // tile t+1 landed
      } else {
        asm volatile("s_waitcnt vmcnt(0)" ::: "memory");  // last tile landed
      }
      __builtin_amdgcn_s_barrier();              // next buffer ready
    }
  }

  const int er = (lane >> 4) * 4;
  #pragma unroll
  for (int mi = 0; mi < 4; ++mi) {
    #pragma unroll
    for (int ni = 0; ni < 4; ++ni) {
      #pragma unroll
      for (int j = 0; j < 4; ++j) {
        const int r = brow + wr + mi * 16 + er + j;
        const int c = bcol + wc + ni * 16 + fr;
        float v = acc[mi][ni][j];
        if (MODE == 0) {
          v = (v + bias[c]) * scale;
          ((unsigned short*)Cout)[(size_t)r * DIM_ + c] = f2bf(v);
        } else if (MODE == 2) {
          ((float*)Cout)[(size_t)r * DIM_ + c] = v + bias[c];
        } else {                       // MODE 34
          v += frac[r] * bb[c];
          const int bb_ = r >> 8, key = r & 255;
          const int hh = c >> 6, dd = c & 63;
          const int bh = bb_ * NH_ + hh;
          size_t idx;
          if (isV) {
            idx = (size_t)bh * 16384 +
                ((key >> 5) * 4 + (dd >> 4)) * 512 + ((key >> 3) & 3) * 128 +
                (dd & 15) * 8 + (key & 7) + 786432;
          } else {
            const int tt = key >> 5, g = (key >> 3) & 3, sub = (key >> 2) & 1, jj = key & 3;
            const int frk = g * 4 + jj;
            idx = (size_t)bh * 16384 +
                (((tt * 2 + sub) * 2) + (dd >> 5)) * 512 + ((dd >> 3) & 3) * 128 +
                frk * 8 + (dd & 7);
          }
          ((unsigned short*)Cout)[idx] = f2bf(v);
        }
      }
    }
  }
}

// ---------------------------------------------------------------------------
// Fused low-rank attention — 512-thread blocks (8 waves x 16 q-rows), grid
// 32x48, launch_bounds(512,4).  K staged in LDS (32 KB), V from L2-resident
// Vf.  VALU diet (r21-verified at the accuracy floor): raw v_exp_f32 +
// v_cvt_pk_bf16_f32 RNE pack; max-subtract + normalize-before-pack kept.
// ---------------------------------------------------------------------------
__global__ __launch_bounds__(512, 4) void attn_fused(
    const unsigned short* __restrict__ Qh,   // [4,4096,768] bf16 (pre-scaled)
    const unsigned short* __restrict__ Kf,   // [48][16384] bf16 fragment-major
    const unsigned short* __restrict__ Vf,   // [48][16384] bf16 fragment-major
    unsigned short* __restrict__ ctx)        // [4,4096,768] bf16
{
  __shared__ __align__(16) unsigned short Ks[16384];   // 32 KB
  const int tid  = threadIdx.x;          // 0..511
  const int lane = tid & 63;
  const int wave = tid >> 6;             // 0..7
  const int bh = blockIdx.y;
  const int b = bh / NH_, h = bh % NH_;
  const int fr = lane & 15;
  const int hi = lane >> 4;
  const int qrow = blockIdx.x * 128 + wave * 16;

  // ---- stage K head (32 KB) once: linear global -> linear LDS (4 shots)
  {
    const unsigned short* kg = Kf + (size_t)bh * 16384 + tid * 8;
    #pragma unroll
    for (int i = 0; i < 4; ++i)
      __builtin_amdgcn_global_load_lds((const u32g*)(kg + i * 4096),
                                       (u32l*)&Ks[i * 4096 + tid * 8], 16, 0, 0);
  }

  // ---- Q fragments (global; issued before the barrier drain)
  const unsigned short* qp = Qh + (size_t)(b * SEQ_ + qrow + fr) * DIM_ + h * HD_ + hi * 8;
  const bf8 q0 = *(const bf8*)qp;
  const bf8 q1 = *(const bf8*)(qp + 32);

  __syncthreads();   // drains DMA vmcnt; Ks visible block-wide

  // ---- QK^T: 8 key-groups of 32
  f32x4 scA[8], scB[8];
  __builtin_amdgcn_s_setprio(1);
  #pragma unroll
  for (int s = 0; s < 8; ++s) {
    const bf8 ka0 = *(const bf8*)&Ks[(s * 4 + 0) * 512 + lane * 8];
    const bf8 ka1 = *(const bf8*)&Ks[(s * 4 + 1) * 512 + lane * 8];
    const bf8 kb0 = *(const bf8*)&Ks[(s * 4 + 2) * 512 + lane * 8];
    const bf8 kb1 = *(const bf8*)&Ks[(s * 4 + 3) * 512 + lane * 8];
    f32x4 x = (f32x4){0.f, 0.f, 0.f, 0.f};
    x = __builtin_amdgcn_mfma_f32_16x16x32_bf16(ka0, q0, x, 0, 0, 0);
    x = __builtin_amdgcn_mfma_f32_16x16x32_bf16(ka1, q1, x, 0, 0, 0);
    scA[s] = x;
    f32x4 y = (f32x4){0.f, 0.f, 0.f, 0.f};
    y = __builtin_amdgcn_mfma_f32_16x16x32_bf16(kb0, q0, y, 0, 0, 0);
    y = __builtin_amdgcn_mfma_f32_16x16x32_bf16(kb1, q1, y, 0, 0, 0);
    scB[s] = y;
  }
  __builtin_amdgcn_s_setprio(0);

  // ---- softmax max: f32x4-elementwise tree + horizontal + 2 shfl
  f32x4 tm[8];
  #pragma unroll
  for (int s = 0; s < 8; ++s) tm[s] = max4(scA[s], scB[s]);
  tm[0] = max4(tm[0], tm[4]); tm[1] = max4(tm[1], tm[5]);
  tm[2] = max4(tm[2], tm[6]); tm[3] = max4(tm[3], tm[7]);
  tm[0] = max4(tm[0], tm[2]); tm[1] = max4(tm[1], tm[3]);
  tm[0] = max4(tm[0], tm[1]);
  float m = fmaxf(fmaxf(tm[0][0], tm[0][1]), fmaxf(tm[0][2], tm[0][3]));
  m = fmaxf(m, __shfl_xor(m, 16));
  m = fmaxf(m, __shfl_xor(m, 32));

  // ---- exp2 (raw v_exp_f32) + vector partial sums
  f32x4 uA = (f32x4){0.f, 0.f, 0.f, 0.f};
  f32x4 uB = (f32x4){0.f, 0.f, 0.f, 0.f};
  #pragma unroll
  for (int s = 0; s < 8; ++s) {
    #pragma unroll
    for (int j = 0; j < 4; ++j) {
      scA[s][j] = fexp2(scA[s][j] - m);
      scB[s][j] = fexp2(scB[s][j] - m);
    }
    uA += scA[s];
    uB += scB[s];
  }
  const f32x4 uv = uA + uB;
  float sum = (uv[0] + uv[1]) + (uv[2] + uv[3]);
  sum += __shfl_xor(sum, 16);
  sum += __shfl_xor(sum, 32);
  const float inv = 1.f / sum;

  // ---- pack normalized P via v_cvt_pk_bf16_f32 (RNE) into K=32 A-frags
  bf8 pa[8];
  #pragma unroll
  for (int s = 0; s < 8; ++s) {
    u32x4 w;
    w[0] = cvtpk(scA[s][0] * inv, scA[s][1] * inv);
    w[1] = cvtpk(scA[s][2] * inv, scA[s][3] * inv);
    w[2] = cvtpk(scB[s][0] * inv, scB[s][1] * inv);
    w[3] = cvtpk(scB[s][2] * inv, scB[s][3] * inv);
    pa[s] = __builtin_bit_cast(bf8, w);
  }

  // ---- PV: K=256 as 8 K=32 steps, 4 d-tiles; V fragments from global/L2
  const unsigned short* vb = Vf + (size_t)bh * 16384 + lane * 8;
  f32x4 acc[4];
  #pragma unroll
  for (int ct = 0; ct < 4; ++ct) acc[ct] = (f32x4){0.f, 0.f, 0.f, 0.f};
  __builtin_amdgcn_s_setprio(1);
  #pragma unroll
  for (int s = 0; s < 8; ++s) {
    #pragma unroll
    for (int ct = 0; ct < 4; ++ct) {
      const bf8 vf = *(const bf8*)(vb + (s * 4 + ct) * 512);
      acc[ct] = __builtin_amdgcn_mfma_f32_16x16x32_bf16(pa[s], vf, acc[ct], 0, 0, 0);
    }
  }
  __builtin_amdgcn_s_setprio(0);

  // ---- ctx write: lane holds O[q=qrow+hi*4+j][d=h*64+ct*16+fr]
  #pragma unroll
  for (int ct = 0; ct < 4; ++ct)
    #pragma unroll
    for (int j = 0; j < 4; ++j)
      ctx[(size_t)(b * SEQ_ + qrow + hi * 4 + j) * DIM_ + h * HD_ + ct * 16 + fr] =
          f2bf(acc[ct][j]);
}

// ---------------------------------------------------------------------------
extern "C" void kernel_launch(void* const* d_in, const int* in_sizes, int n_in,
                              void* d_out, int out_size, void* d_ws, size_t ws_size,
                              hipStream_t stream) {
  const float* query = (const float*)d_in[0];
  const float* key   = (const float*)d_in[1];
  const float* value = (const float*)d_in[2];
  const float* mask  = (const float*)d_in[3];
  const float* Wq    = (const float*)d_in[4];
  const float* bq    = (const float*)d_in[5];
  const float* Wk    = (const float*)d_in[6];
  const float* bk    = (const float*)d_in[7];
  const float* Wv    = (const float*)d_in[8];
  const float* bv    = (const float*)d_in[9];
  const float* Wo    = (const float*)d_in[10];
  const float* bo    = (const float*)d_in[11];
  float* out = (float*)d_out;

  char* ws = (char*)d_ws;
  unsigned short* Qh  = (unsigned short*)ws;                  // 25,165,824 B
  unsigned short* ctx = (unsigned short*)(ws + 25165824);     // 25,165,824 B
  unsigned short* pK  = (unsigned short*)(ws + 50331648);     //  1,572,864 B
  unsigned short* pV  = (unsigned short*)(ws + 51904512);     //  1,572,864 B (pK+786432 elems)
  unsigned short* Kf  = (unsigned short*)(ws + 53477376);     //  1,572,864 B
  unsigned short* Vf  = (unsigned short*)(ws + 55050240);     //  1,572,864 B (Kf+786432 elems)
  float*          frac = (float*)(ws + 56623104);             //      4,096 B
  unsigned short* Wbf = (unsigned short*)(ws + 56627200);     //  4,718,592 B
  unsigned short* Qbf = ctx;   // ctx region is dead until attn

  const float qscale = 0.125f * LOG2E;   // 1/sqrt(64), e->2 exponent base

  prep_kernel<<<dim3(3456), dim3(384), 0, stream>>>(
      key, value, mask, query, Wq, Wk, Wv, Wo, pK, pV, frac, Qbf, Wbf);
  gemm_bt<0, 1><<<dim3(768), dim3(256), 0, stream>>>(
      Qbf, Wbf, bq, nullptr, nullptr, Qh, qscale);
  gemm_bt<34, 0><<<dim3(8, 6, 2), dim3(256), 0, stream>>>(
      pK, Wbf + DIM_*DIM_, bk, bv, frac, Kf, 1.f);
  attn_fused<<<dim3(32, 48), dim3(512), 0, stream>>>(Qh, Kf, Vf, ctx);
  gemm_bt<2, 1><<<dim3(768), dim3(256), 0, stream>>>(
      ctx, Wbf + 3*DIM_*DIM_, bo, nullptr, nullptr, out, 1.f);
}

// Round 27
// 127.113 us; speedup vs baseline: 1.2100x; 1.2100x over previous
//
#include <hip/hip_runtime.h>

#define BS_   4
#define SEQ_  4096
#define DIM_  768
#define NH_   12
#define HD_   64
#define LK_   256

typedef __attribute__((ext_vector_type(8))) short          bf8;
typedef __attribute__((ext_vector_type(8))) unsigned short us8;
typedef __attribute__((ext_vector_type(4))) unsigned short us4;
typedef __attribute__((ext_vector_type(4))) float          f32x4;
typedef __attribute__((ext_vector_type(4))) unsigned int   u32x4;

typedef unsigned int u32g __attribute__((address_space(1)));
typedef unsigned int u32l __attribute__((address_space(3)));

#define LOG2E 1.44269504088896340736f

__device__ __forceinline__ unsigned short f2bf(float f) {
  unsigned u = __builtin_bit_cast(unsigned, f);
  u += 0x7fffu + ((u >> 16) & 1u);   // round-to-nearest-even
  return (unsigned short)(u >> 16);
}

__device__ __forceinline__ us8 cvt8(const float* __restrict__ p) {
  const float4 a = *(const float4*)p;
  const float4 b = *(const float4*)(p + 4);
  us8 r;
  r[0] = f2bf(a.x); r[1] = f2bf(a.y); r[2] = f2bf(a.z); r[3] = f2bf(a.w);
  r[4] = f2bf(b.x); r[5] = f2bf(b.y); r[6] = f2bf(b.z); r[7] = f2bf(b.w);
  return r;
}

__device__ __forceinline__ f32x4 max4(f32x4 a, f32x4 b) {
  f32x4 r;
  r[0] = fmaxf(a[0], b[0]); r[1] = fmaxf(a[1], b[1]);
  r[2] = fmaxf(a[2], b[2]); r[3] = fmaxf(a[3], b[3]);
  return r;
}

// raw transcendental (r6/r21-verified): input <= 0 after max-subtract, safe
__device__ __forceinline__ float fexp2(float x) {
  float r; asm("v_exp_f32 %0, %1" : "=v"(r) : "v"(x)); return r;
}
// packed f32x2 -> bf16x2, RNE (r21-verified at the accuracy floor)
__device__ __forceinline__ unsigned cvtpk(float lo, float hi) {
  unsigned r; asm("v_cvt_pk_bf16_f32 %0, %1, %2" : "=v"(r) : "v"(lo), "v"(hi));
  return r;
}

// ---------------------------------------------------------------------------
// Merged prep dispatch (384 threads) — best-measured r22 variant:
//  blocks 0..1023   : masked 16-window pool -> pK/pV + frac (compacted
//                     window list, 8 loads in flight).
//  blocks 1024..3455: bf16 conversion of query (-> Qbf) + weights (-> Wbf),
//                     two independent 32B chunks per thread.
// ---------------------------------------------------------------------------
__global__ __launch_bounds__(384) void prep_kernel(
    const float* __restrict__ key, const float* __restrict__ value,
    const float* __restrict__ mask, const float* __restrict__ query,
    const float* __restrict__ Wq, const float* __restrict__ Wk,
    const float* __restrict__ Wv, const float* __restrict__ Wo,
    unsigned short* __restrict__ pk, unsigned short* __restrict__ pv,
    float* __restrict__ frac,
    unsigned short* __restrict__ Qbf, unsigned short* __restrict__ Wbf)
{
  const int bid = blockIdx.x;
  const int tid = threadIdx.x;
  if (bid < 1024) {                    // ---- pool path
    const int b = bid >> 8;
    const int l = bid & 255;
    __shared__ float keep[16];
    __shared__ int   wlist[16];
    __shared__ float wwt[16];
    __shared__ int   nk4s;
    if (tid < 16) keep[tid] = (mask[b * SEQ_ + l * 16 + tid] >= 0.f) ? 1.f : 0.f;
    __syncthreads();
    if (tid == 0) {
      int n = 0; float cnt = 0.f;
      for (int w = 0; w < 16; ++w)
        if (keep[w] != 0.f) { wlist[n] = w; wwt[n] = 1.f; ++n; cnt += 1.f; }
      frac[b * LK_ + l] = cnt * (1.f / 16.f);
      const int n8 = (n + 7) & ~7;
      for (int i = n; i < n8; ++i) { wlist[i] = wlist[0]; wwt[i] = 0.f; }
      if (n == 0) for (int i = 0; i < 8; ++i) { wlist[i] = 0; wwt[i] = 0.f; }
      nk4s = (n == 0) ? 0 : n8;
    }
    __syncthreads();
    const int nk8 = nk4s;
    const int isV = tid >= 192;
    const int c = isV ? tid - 192 : tid;          // float4 chunk 0..191
    const float* src = isV ? value : key;
    const float* base = src + (size_t)(b * SEQ_ + l * 16) * DIM_ + c * 4;
    float4 acc = make_float4(0.f, 0.f, 0.f, 0.f);
    for (int i = 0; i < nk8; i += 8) {
      #pragma unroll
      for (int u = 0; u < 8; ++u) {
        const float4 v = *(const float4*)(base + (size_t)wlist[i + u] * DIM_);
        const float w = wwt[i + u];
        acc.x = fmaf(w, v.x, acc.x); acc.y = fmaf(w, v.y, acc.y);
        acc.z = fmaf(w, v.z, acc.z); acc.w = fmaf(w, v.w, acc.w);
      }
    }
    const float s = 1.f / 16.f;
    unsigned short* dst = isV ? pv : pk;
    us4 o4;
    o4[0] = f2bf(acc.x * s); o4[1] = f2bf(acc.y * s);
    o4[2] = f2bf(acc.z * s); o4[3] = f2bf(acc.w * s);
    *(us4*)(dst + (size_t)(b * LK_ + l) * DIM_ + c * 4) = o4;
    return;
  }
  // ---- conversion path: two chunks per thread, loads independent
  const int QN8 = (BS_ * SEQ_ * DIM_) / 8;        // 1572864
  const int WN8 = (DIM_ * DIM_) / 8;              // 73728
  const int i0 = (bid - 1024) * 768 + tid;
  #pragma unroll
  for (int u = 0; u < 2; ++u) {
    const int i = i0 + u * 384;
    if (i < QN8) { *(us8*)(Qbf + (size_t)i * 8) = cvt8(query + (size_t)i * 8); continue; }
    int j = i - QN8;
    const float* src; unsigned short* dst;
    if      (j <     WN8) { src = Wq; dst = Wbf;                   }
    else if (j < 2 * WN8) { src = Wk; dst = Wbf + DIM_*DIM_;     j -=     WN8; }
    else if (j < 3 * WN8) { src = Wv; dst = Wbf + 2*DIM_*DIM_;   j -= 2 * WN8; }
    else if (j < 4 * WN8) { src = Wo; dst = Wbf + 3*DIM_*DIM_;   j -= 3 * WN8; }
    else continue;
    *(us8*)(dst + (size_t)j * 8) = cvt8(src + (size_t)j * 8);
  }
}

// ---------------------------------------------------------------------------
// C = A @ B^T (+ epilogue).  128x128 tile, BK=64, 4 waves, 16x16x32 bf16
// MFMA, double-buffered LDS with COUNTED vmcnt (T3+T4, r20-verified):
// raw s_barrier + vmcnt(8) keeps 8 loads in flight across the barrier.
// XOR chunk-swizzle both sides (src chunk=(tid&7)^(srow&7); read c^(row&7)).
// (r26 lesson: occupancy is GRID-capped at 3 blocks/CU — 768 blocks/256 CU;
//  BK=32 halved LDS for nothing and doubled barrier count, −12 us.)
// MODE 0: out_bf16 = (acc + bias[c]) * scale               (Q projection)
// MODE 2: out_f32  = acc + bias[c]                         (output projection)
// MODE 34: fused K/V projection pair, blockIdx.z selects Kf/Vf layouts.
// ---------------------------------------------------------------------------
template<int MODE, int SWZ>
__global__ __launch_bounds__(256) void gemm_bt(
    const void* __restrict__ Aptr_, const void* __restrict__ Bptr_,
    const float* __restrict__ bias, const float* __restrict__ bias2,
    const float* __restrict__ frac,
    void* __restrict__ Cout, float scale)
{
  constexpr int K  = DIM_;
  constexpr int BK = 64;
  constexpr int NT = K / BK;           // 12
  __shared__ __align__(16) unsigned short lA[2][128 * BK];   // 2 x 16 KB
  __shared__ __align__(16) unsigned short lB[2][128 * BK];   // 2 x 16 KB
  const int tid  = threadIdx.x;
  const int lane = tid & 63;
  const int wave = tid >> 6;

  int bx, by;
  if (SWZ) {
    const int r = (blockIdx.x & 7) * 96 + (blockIdx.x >> 3);
    bx = r / 6; by = r % 6;
  } else {
    bx = blockIdx.x; by = blockIdx.y;
  }
  const int brow = bx * 128;
  const int bcol = by * 128;

  const unsigned short* A  = (const unsigned short*)Aptr_;
  const unsigned short* Bw = (const unsigned short*)Bptr_;
  const float* bb = bias;
  int isV = 0;
  if (MODE == 34) {
    isV = blockIdx.z;
    A  += (size_t)isV * (BS_ * LK_ * DIM_);    // pV follows pK
    Bw += (size_t)isV * (DIM_ * DIM_);         // Wv follows Wk
    if (isV) bb = bias2;
  }

  const int wr = (wave >> 1) * 64;
  const int wc = (wave & 1) * 64;
  const int fr = lane & 15;
  const int hi = lane >> 4;
  const int rx = fr & 7;               // read-side swizzle key (row & 7)

  f32x4 acc[4][4];
  #pragma unroll
  for (int i = 0; i < 4; ++i)
    #pragma unroll
    for (int j = 0; j < 4; ++j) acc[i][j] = (f32x4){0.f, 0.f, 0.f, 0.f};

  const int srow = tid >> 3;                       // 0..31 (row within shot)
  const int schk = ((tid & 7) ^ (srow & 7)) * 8;   // swizzled source chunk

  auto STAGE = [&](int t, int b) {     // 8 VMEM instructions per wave
    const int k0 = t * BK;
    #pragma unroll
    for (int s = 0; s < 4; ++s) {
      __builtin_amdgcn_global_load_lds(
          (const u32g*)(A + (size_t)(brow + srow + s * 32) * K + k0 + schk),
          (u32l*)&lA[b][s * 2048 + tid * 8], 16, 0, 0);
      __builtin_amdgcn_global_load_lds(
          (const u32g*)(Bw + (size_t)(bcol + srow + s * 32) * K + k0 + schk),
          (u32l*)&lB[b][s * 2048 + tid * 8], 16, 0, 0);
    }
  };

  auto COMPUTE = [&](int b) {
    #pragma unroll
    for (int ks = 0; ks < 2; ++ks) {
      bf8 af[4], bfv[4];
      const int c = ks * 4 + hi;       // logical chunk 0..7
      const int pc = (c ^ rx) * 8;     // physical chunk offset (elems)
      #pragma unroll
      for (int mi = 0; mi < 4; ++mi)
        af[mi] = *(const bf8*)&lA[b][(wr + mi * 16 + fr) * BK + pc];
      #pragma unroll
      for (int ni = 0; ni < 4; ++ni)
        bfv[ni] = *(const bf8*)&lB[b][(wc + ni * 16 + fr) * BK + pc];
      #pragma unroll
      for (int mi = 0; mi < 4; ++mi)
        #pragma unroll
        for (int ni = 0; ni < 4; ++ni)
          acc[mi][ni] = __builtin_amdgcn_mfma_f32_16x16x32_bf16(af[mi], bfv[ni], acc[mi][ni], 0, 0, 0);
    }
  };

  // ---- prologue: two tiles in flight, wait only for the first
  STAGE(0, 0);
  STAGE(1, 1);
  asm volatile("s_waitcnt vmcnt(8)" ::: "memory");
  __builtin_amdgcn_s_barrier();

  #pragma unroll 2
  for (int t = 0; t < NT; ++t) {
    COMPUTE(t & 1);
    if (t + 1 < NT) {
      __builtin_amdgcn_s_barrier();              // all waves done reading buf
      if (t + 2 < NT) {
        STAGE(t + 2, t & 1);                     // refill freed buffer
        asm volatile("s_waitcnt vmcnt(8)" ::: "memory");  // tile t+1 landed
      } else {
        asm volatile("s_waitcnt vmcnt(0)" ::: "memory");  // last tile landed
      }
      __builtin_amdgcn_s_barrier();              // next buffer ready
    }
  }

  const int er = (lane >> 4) * 4;
  #pragma unroll
  for (int mi = 0; mi < 4; ++mi) {
    #pragma unroll
    for (int ni = 0; ni < 4; ++ni) {
      #pragma unroll
      for (int j = 0; j < 4; ++j) {
        const int r = brow + wr + mi * 16 + er + j;
        const int c = bcol + wc + ni * 16 + fr;
        float v = acc[mi][ni][j];
        if (MODE == 0) {
          v = (v + bias[c]) * scale;
          ((unsigned short*)Cout)[(size_t)r * DIM_ + c] = f2bf(v);
        } else if (MODE == 2) {
          ((float*)Cout)[(size_t)r * DIM_ + c] = v + bias[c];
        } else {                       // MODE 34
          v += frac[r] * bb[c];
          const int bb_ = r >> 8, key = r & 255;
          const int hh = c >> 6, dd = c & 63;
          const int bh = bb_ * NH_ + hh;
          size_t idx;
          if (isV) {
            idx = (size_t)bh * 16384 +
                ((key >> 5) * 4 + (dd >> 4)) * 512 + ((key >> 3) & 3) * 128 +
                (dd & 15) * 8 + (key & 7) + 786432;
          } else {
            const int tt = key >> 5, g = (key >> 3) & 3, sub = (key >> 2) & 1, jj = key & 3;
            const int frk = g * 4 + jj;
            idx = (size_t)bh * 16384 +
                (((tt * 2 + sub) * 2) + (dd >> 5)) * 512 + ((dd >> 3) & 3) * 128 +
                frk * 8 + (dd & 7);
          }
          ((unsigned short*)Cout)[idx] = f2bf(v);
        }
      }
    }
  }
}

// ---------------------------------------------------------------------------
// Fused low-rank attention — 512-thread blocks (8 waves x 16 q-rows), grid
// 32x48, launch_bounds(512,4).  K staged in LDS (32 KB), V from L2-resident
// Vf.  VALU diet (r21-verified at the accuracy floor): raw v_exp_f32 +
// v_cvt_pk_bf16_f32 RNE pack; max-subtract + normalize-before-pack kept.
// ---------------------------------------------------------------------------
__global__ __launch_bounds__(512, 4) void attn_fused(
    const unsigned short* __restrict__ Qh,   // [4,4096,768] bf16 (pre-scaled)
    const unsigned short* __restrict__ Kf,   // [48][16384] bf16 fragment-major
    const unsigned short* __restrict__ Vf,   // [48][16384] bf16 fragment-major
    unsigned short* __restrict__ ctx)        // [4,4096,768] bf16
{
  __shared__ __align__(16) unsigned short Ks[16384];   // 32 KB
  const int tid  = threadIdx.x;          // 0..511
  const int lane = tid & 63;
  const int wave = tid >> 6;             // 0..7
  const int bh = blockIdx.y;
  const int b = bh / NH_, h = bh % NH_;
  const int fr = lane & 15;
  const int hi = lane >> 4;
  const int qrow = blockIdx.x * 128 + wave * 16;

  // ---- stage K head (32 KB) once: linear global -> linear LDS (4 shots)
  {
    const unsigned short* kg = Kf + (size_t)bh * 16384 + tid * 8;
    #pragma unroll
    for (int i = 0; i < 4; ++i)
      __builtin_amdgcn_global_load_lds((const u32g*)(kg + i * 4096),
                                       (u32l*)&Ks[i * 4096 + tid * 8], 16, 0, 0);
  }

  // ---- Q fragments (global; issued before the barrier drain)
  const unsigned short* qp = Qh + (size_t)(b * SEQ_ + qrow + fr) * DIM_ + h * HD_ + hi * 8;
  const bf8 q0 = *(const bf8*)qp;
  const bf8 q1 = *(const bf8*)(qp + 32);

  __syncthreads();   // drains DMA vmcnt; Ks visible block-wide

  // ---- QK^T: 8 key-groups of 32
  f32x4 scA[8], scB[8];
  __builtin_amdgcn_s_setprio(1);
  #pragma unroll
  for (int s = 0; s < 8; ++s) {
    const bf8 ka0 = *(const bf8*)&Ks[(s * 4 + 0) * 512 + lane * 8];
    const bf8 ka1 = *(const bf8*)&Ks[(s * 4 + 1) * 512 + lane * 8];
    const bf8 kb0 = *(const bf8*)&Ks[(s * 4 + 2) * 512 + lane * 8];
    const bf8 kb1 = *(const bf8*)&Ks[(s * 4 + 3) * 512 + lane * 8];
    f32x4 x = (f32x4){0.f, 0.f, 0.f, 0.f};
    x = __builtin_amdgcn_mfma_f32_16x16x32_bf16(ka0, q0, x, 0, 0, 0);
    x = __builtin_amdgcn_mfma_f32_16x16x32_bf16(ka1, q1, x, 0, 0, 0);
    scA[s] = x;
    f32x4 y = (f32x4){0.f, 0.f, 0.f, 0.f};
    y = __builtin_amdgcn_mfma_f32_16x16x32_bf16(kb0, q0, y, 0, 0, 0);
    y = __builtin_amdgcn_mfma_f32_16x16x32_bf16(kb1, q1, y, 0, 0, 0);
    scB[s] = y;
  }
  __builtin_amdgcn_s_setprio(0);

  // ---- softmax max: f32x4-elementwise tree + horizontal + 2 shfl
  f32x4 tm[8];
  #pragma unroll
  for (int s = 0; s < 8; ++s) tm[s] = max4(scA[s], scB[s]);
  tm[0] = max4(tm[0], tm[4]); tm[1] = max4(tm[1], tm[5]);
  tm[2] = max4(tm[2], tm[6]); tm[3] = max4(tm[3], tm[7]);
  tm[0] = max4(tm[0], tm[2]); tm[1] = max4(tm[1], tm[3]);
  tm[0] = max4(tm[0], tm[1]);
  float m = fmaxf(fmaxf(tm[0][0], tm[0][1]), fmaxf(tm[0][2], tm[0][3]));
  m = fmaxf(m, __shfl_xor(m, 16));
  m = fmaxf(m, __shfl_xor(m, 32));

  // ---- exp2 (raw v_exp_f32) + vector partial sums
  f32x4 uA = (f32x4){0.f, 0.f, 0.f, 0.f};
  f32x4 uB = (f32x4){0.f, 0.f, 0.f, 0.f};
  #pragma unroll
  for (int s = 0; s < 8; ++s) {
    #pragma unroll
    for (int j = 0; j < 4; ++j) {
      scA[s][j] = fexp2(scA[s][j] - m);
      scB[s][j] = fexp2(scB[s][j] - m);
    }
    uA += scA[s];
    uB += scB[s];
  }
  const f32x4 uv = uA + uB;
  float sum = (uv[0] + uv[1]) + (uv[2] + uv[3]);
  sum += __shfl_xor(sum, 16);
  sum += __shfl_xor(sum, 32);
  const float inv = 1.f / sum;

  // ---- pack normalized P via v_cvt_pk_bf16_f32 (RNE) into K=32 A-frags
  bf8 pa[8];
  #pragma unroll
  for (int s = 0; s < 8; ++s) {
    u32x4 w;
    w[0] = cvtpk(scA[s][0] * inv, scA[s][1] * inv);
    w[1] = cvtpk(scA[s][2] * inv, scA[s][3] * inv);
    w[2] = cvtpk(scB[s][0] * inv, scB[s][1] * inv);
    w[3] = cvtpk(scB[s][2] * inv, scB[s][3] * inv);
    pa[s] = __builtin_bit_cast(bf8, w);
  }

  // ---- PV: K=256 as 8 K=32 steps, 4 d-tiles; V fragments from global/L2
  const unsigned short* vb = Vf + (size_t)bh * 16384 + lane * 8;
  f32x4 acc[4];
  #pragma unroll
  for (int ct = 0; ct < 4; ++ct) acc[ct] = (f32x4){0.f, 0.f, 0.f, 0.f};
  __builtin_amdgcn_s_setprio(1);
  #pragma unroll
  for (int s = 0; s < 8; ++s) {
    #pragma unroll
    for (int ct = 0; ct < 4; ++ct) {
      const bf8 vf = *(const bf8*)(vb + (s * 4 + ct) * 512);
      acc[ct] = __builtin_amdgcn_mfma_f32_16x16x32_bf16(pa[s], vf, acc[ct], 0, 0, 0);
    }
  }
  __builtin_amdgcn_s_setprio(0);

  // ---- ctx write: lane holds O[q=qrow+hi*4+j][d=h*64+ct*16+fr]
  #pragma unroll
  for (int ct = 0; ct < 4; ++ct)
    #pragma unroll
    for (int j = 0; j < 4; ++j)
      ctx[(size_t)(b * SEQ_ + qrow + hi * 4 + j) * DIM_ + h * HD_ + ct * 16 + fr] =
          f2bf(acc[ct][j]);
}

// ---------------------------------------------------------------------------
extern "C" void kernel_launch(void* const* d_in, const int* in_sizes, int n_in,
                              void* d_out, int out_size, void* d_ws, size_t ws_size,
                              hipStream_t stream) {
  const float* query = (const float*)d_in[0];
  const float* key   = (const float*)d_in[1];
  const float* value = (const float*)d_in[2];
  const float* mask  = (const float*)d_in[3];
  const float* Wq    = (const float*)d_in[4];
  const float* bq    = (const float*)d_in[5];
  const float* Wk    = (const float*)d_in[6];
  const float* bk    = (const float*)d_in[7];
  const float* Wv    = (const float*)d_in[8];
  const float* bv    = (const float*)d_in[9];
  const float* Wo    = (const float*)d_in[10];
  const float* bo    = (const float*)d_in[11];
  float* out = (float*)d_out;

  char* ws = (char*)d_ws;
  unsigned short* Qh  = (unsigned short*)ws;                  // 25,165,824 B
  unsigned short* ctx = (unsigned short*)(ws + 25165824);     // 25,165,824 B
  unsigned short* pK  = (unsigned short*)(ws + 50331648);     //  1,572,864 B
  unsigned short* pV  = (unsigned short*)(ws + 51904512);     //  1,572,864 B (pK+786432 elems)
  unsigned short* Kf  = (unsigned short*)(ws + 53477376);     //  1,572,864 B
  unsigned short* Vf  = (unsigned short*)(ws + 55050240);     //  1,572,864 B (Kf+786432 elems)
  float*          frac = (float*)(ws + 56623104);             //      4,096 B
  unsigned short* Wbf = (unsigned short*)(ws + 56627200);     //  4,718,592 B
  unsigned short* Qbf = ctx;   // ctx region is dead until attn

  const float qscale = 0.125f * LOG2E;   // 1/sqrt(64), e->2 exponent base

  prep_kernel<<<dim3(3456), dim3(384), 0, stream>>>(
      key, value, mask, query, Wq, Wk, Wv, Wo, pK, pV, frac, Qbf, Wbf);
  gemm_bt<0, 1><<<dim3(768), dim3(256), 0, stream>>>(
      Qbf, Wbf, bq, nullptr, nullptr, Qh, qscale);
  gemm_bt<34, 0><<<dim3(8, 6, 2), dim3(256), 0, stream>>>(
      pK, Wbf + DIM_*DIM_, bk, bv, frac, Kf, 1.f);
  attn_fused<<<dim3(32, 48), dim3(512), 0, stream>>>(Qh, Kf, Vf, ctx);
  gemm_bt<2, 1><<<dim3(768), dim3(256), 0, stream>>>(
      ctx, Wbf + 3*DIM_*DIM_, bo, nullptr, nullptr, out, 1.f);
}